// Round 1
// baseline (272.351 us; speedup 1.0000x reference)
//
#include <hip/hip_runtime.h>

// Problem constants (image 128x128, TILE_SIZE=64)
#define IMG 128
#define TSZ 64
#define NTILES 4          // (128/64)^2
#define PMAX 2048
#define SELCAP 4096       // LDS sort capacity (>= PMAX + max bucket spill)
#define NHIST 65536       // depth-bits[31:16] histogram buckets
#define NCHUNK 16
#define CHUNK 128         // PMAX / NCHUNK
#define NPIX 4096         // TSZ*TSZ
#define PLANE ((size_t)NTILES * NCHUNK * NPIX)   // 262144 floats per component plane

typedef unsigned int uint32;
typedef unsigned long long u64;

// ---------------------------------------------------------------- zero ws ---
__global__ void zero_ws(uint32* __restrict__ p, int n) {
    int i = blockIdx.x * blockDim.x + threadIdx.x;
    if (i < n) p[i] = 0u;
}

// -------------------------------------------------------------- preprocess --
// Per gaussian: radius/rect (reference get_radius/get_rect), per-tile overlap,
// ballot-aggregated append of 64-bit key (depth_bits<<32 | idx) to per-tile
// candidate list, histogram of depth bits[31:16].
__global__ void preproc(const float* __restrict__ means,
                        const float* __restrict__ cov,
                        const float* __restrict__ depths,
                        uint32* __restrict__ candCount,
                        uint32* __restrict__ hist,
                        u64* __restrict__ cand,
                        int N) {
    int i = blockIdx.x * blockDim.x + threadIdx.x;
    bool active = (i < N);
    float rminx = 0.f, rminy = 0.f, rmaxx = 0.f, rmaxy = 0.f;
    u64 key = 0; uint32 fb = 0;
    if (active) {
        const float4 cv = ((const float4*)cov)[i];           // a, b, c2, d
        float det = cv.x * cv.w - cv.y * cv.z;
        float mid = 0.5f * (cv.x + cv.w);
        float s = sqrtf(fmaxf(mid * mid - det, 0.1f));
        float lam = fmaxf(mid + s, mid - s);
        float radius = 3.0f * ceilf(sqrtf(lam));
        const float2 m = ((const float2*)means)[i];
        rminx = fminf(fmaxf(m.x - radius, 0.f), (float)(IMG - 1));
        rmaxx = fminf(fmaxf(m.x + radius, 0.f), (float)(IMG - 1));
        rminy = fminf(fmaxf(m.y - radius, 0.f), (float)(IMG - 1));
        rmaxy = fminf(fmaxf(m.y + radius, 0.f), (float)(IMG - 1));
        fb = __float_as_uint(depths[i]);                     // positive -> monotone bits
        key = ((u64)fb << 32) | (uint32)i;                   // stable (depth, idx) order
    }
    int lane = threadIdx.x & 63;
    #pragma unroll
    for (int t = 0; t < NTILES; t++) {
        float wmin = (float)((t & 1) * TSZ), hmin = (float)((t >> 1) * TSZ);
        float wmax = wmin + (float)(TSZ - 1), hmax = hmin + (float)(TSZ - 1);
        bool ov = active &&
                  (fminf(rmaxx, wmax) > fmaxf(rminx, wmin)) &&
                  (fminf(rmaxy, hmax) > fmaxf(rminy, hmin));
        u64 mask = __ballot(ov);
        if (ov) {
            int leader = __ffsll((unsigned long long)mask) - 1;
            uint32 rank = (uint32)__popcll(mask & ((1ULL << lane) - 1ULL));
            uint32 base = 0;
            if (lane == leader) base = atomicAdd(&candCount[t], (uint32)__popcll(mask));
            base = __shfl(base, leader);
            cand[(size_t)t * N + base + rank] = key;
            atomicAdd(&hist[t * NHIST + (fb >> 16)], 1u);
        }
    }
}

// ------------------------------------------------------------- select+sort --
// One workgroup per tile: scan histogram for the bucket holding the 2048th
// smallest depth, compact candidates with bucket <= b* into LDS, bitonic-sort
// (exact (depth,idx) order), emit PMAX render-param records (pad: opacity=0).
__global__ __launch_bounds__(1024) void select_sort(
        const uint32* __restrict__ hist,
        const uint32* __restrict__ candCount,
        const u64* __restrict__ cand, int N,
        const float* __restrict__ means, const float* __restrict__ cov,
        const float* __restrict__ color, const float* __restrict__ opac,
        float* __restrict__ params) {
    int tile = blockIdx.x, tid = threadIdx.x;
    __shared__ u64 keys[SELCAP];
    __shared__ uint32 part[1024];
    __shared__ uint32 sBstar, sCount;
    if (tid == 0) { sBstar = NHIST - 1; sCount = 0; }

    const uint32* h = hist + (size_t)tile * NHIST;
    uint32 local = 0;
    #pragma unroll 4
    for (int b = 0; b < 64; b++) local += h[tid * 64 + b];
    part[tid] = local;
    __syncthreads();
    // Hillis-Steele inclusive scan over 1024 partials
    for (int off = 1; off < 1024; off <<= 1) {
        uint32 v = part[tid];
        uint32 u = (tid >= off) ? part[tid - off] : 0u;
        __syncthreads();
        part[tid] = v + u;
        __syncthreads();
    }
    uint32 incl = part[tid], excl = incl - local;
    if (excl < PMAX && incl >= PMAX) {        // unique crossing thread
        uint32 cum = excl;
        for (int b = 0; b < 64; b++) {
            cum += h[tid * 64 + b];
            if (cum >= PMAX) { sBstar = (uint32)(tid * 64 + b); break; }
        }
    }
    __syncthreads();
    uint32 bstar = sBstar;

    uint32 cnt = candCount[tile]; if (cnt > (uint32)N) cnt = (uint32)N;
    const u64* cd = cand + (size_t)tile * N;
    for (uint32 i = tid; i < cnt; i += 1024) {
        u64 k = cd[i];
        if ((uint32)(k >> 48) <= bstar) {
            uint32 pos = atomicAdd(&sCount, 1u);
            if (pos < SELCAP) keys[pos] = k;
        }
    }
    __syncthreads();
    uint32 m = sCount < SELCAP ? sCount : SELCAP;
    for (uint32 i = tid; i < SELCAP; i += 1024)
        if (i >= m) keys[i] = ~0ULL;
    __syncthreads();

    // bitonic sort SELCAP keys ascending
    for (uint32 k = 2; k <= SELCAP; k <<= 1) {
        for (uint32 j = k >> 1; j > 0; j >>= 1) {
            for (uint32 i = tid; i < SELCAP; i += 1024) {
                uint32 l = i ^ j;
                if (l > i) {
                    u64 a = keys[i], b = keys[l];
                    bool asc = ((i & k) == 0);
                    if (asc ? (a > b) : (a < b)) { keys[i] = b; keys[l] = a; }
                }
            }
            __syncthreads();
        }
    }

    // emit params: {mx,my,c00,c01+c10} {c11,op,r,g} {b,depth,0,0}
    for (uint32 slot = tid; slot < PMAX; slot += 1024) {
        u64 kk = keys[slot];
        float4 p0 = {0.f,0.f,0.f,0.f}, p1 = {0.f,0.f,0.f,0.f}, p2 = {0.f,0.f,0.f,0.f};
        if (kk != ~0ULL) {
            uint32 idx = (uint32)(kk & 0xffffffffu);
            float a = cov[4*idx], b = cov[4*idx+1], c2 = cov[4*idx+2], d = cov[4*idx+3];
            float invdet = 1.0f / fmaxf(a * d - b * c2, 1e-6f);
            p0.x = means[2*idx]; p0.y = means[2*idx+1];
            p0.z = d * invdet;                 // c00
            p0.w = -(b + c2) * invdet;         // c01 + c10
            p1.x = a * invdet;                 // c11
            p1.y = opac[idx];
            p1.z = color[3*idx]; p1.w = color[3*idx+1];
            p2.x = color[3*idx+2];
            p2.y = __uint_as_float((uint32)(kk >> 32));   // depth
        }
        float4* P = (float4*)(params + ((size_t)tile * PMAX + slot) * 12);
        P[0] = p0; P[1] = p1; P[2] = p2;
    }
}

// ------------------------------------------------------------------ render --
// Block = 256 pixels of one tile, one chunk of 128 gaussians. Front-to-back
// compositing with local T starting at 1; partial (T, sums) per chunk stored
// SoA for coalescing; combine kernel folds chunks via (T1*T2, S1 + T1*S2).
__global__ __launch_bounds__(256) void render(const float* __restrict__ params,
                                              float* __restrict__ partials) {
    int tile = blockIdx.z, chunk = blockIdx.y;
    int p = blockIdx.x * 256 + threadIdx.x;        // 0..4095 within tile
    __shared__ float4 gp[CHUNK * 3];
    const float4* src = (const float4*)(params + ((size_t)tile * PMAX + (size_t)chunk * CHUNK) * 12);
    for (int j = threadIdx.x; j < CHUNK * 3; j += 256) gp[j] = src[j];
    __syncthreads();

    float px = (float)((tile & 1) * TSZ + (p & 63));
    float py = (float)((tile >> 1) * TSZ + (p >> 6));
    float T = 1.f, cr = 0.f, cg = 0.f, cb = 0.f, dep = 0.f, acc = 0.f;
    #pragma unroll 8
    for (int g = 0; g < CHUNK; g++) {
        float4 p0 = gp[3*g], p1 = gp[3*g+1], p2 = gp[3*g+2];
        float dx = px - p0.x, dy = py - p0.y;
        float power = -0.5f * (dx*dx*p0.z + dy*dy*p1.x + dx*dy*p0.w);
        float alpha = fminf(__expf(power) * p1.y, 0.99f);
        float w = alpha * T;
        cr += w * p1.z; cg += w * p1.w; cb += w * p2.x;
        dep += w * p2.y; acc += w;
        T *= (1.f - alpha);
    }
    size_t base = ((size_t)tile * NCHUNK + chunk) * NPIX + (size_t)p;
    partials[0*PLANE + base] = T;
    partials[1*PLANE + base] = cr;
    partials[2*PLANE + base] = cg;
    partials[3*PLANE + base] = cb;
    partials[4*PLANE + base] = dep;
    partials[5*PLANE + base] = acc;
}

// ----------------------------------------------------------------- combine --
__global__ __launch_bounds__(256) void combine(const float* __restrict__ partials,
                                               float* __restrict__ out) {
    int q = blockIdx.x * 256 + threadIdx.x;        // 0..16383
    int tile = q >> 12, p = q & (NPIX - 1);
    float T = 1.f, cr = 0.f, cg = 0.f, cb = 0.f, dep = 0.f, acc = 0.f;
    #pragma unroll
    for (int c = 0; c < NCHUNK; c++) {
        size_t base = ((size_t)tile * NCHUNK + c) * NPIX + (size_t)p;
        float Tk = partials[0*PLANE + base];
        cr  += T * partials[1*PLANE + base];
        cg  += T * partials[2*PLANE + base];
        cb  += T * partials[3*PLANE + base];
        dep += T * partials[4*PLANE + base];
        acc += T * partials[5*PLANE + base];
        T *= Tk;
    }
    int gx = (tile & 1) * TSZ + (p & 63);
    int gy = (tile >> 1) * TSZ + (p >> 6);
    int pix = gy * IMG + gx;
    float wb = 1.f - acc;                           // WHITE_BKGD
    out[3*pix+0] = cr + wb;
    out[3*pix+1] = cg + wb;
    out[3*pix+2] = cb + wb;
    out[IMG*IMG*3 + pix] = dep;
    out[IMG*IMG*4 + pix] = acc;
}

// ------------------------------------------------------------------ launch --
extern "C" void kernel_launch(void* const* d_in, const int* in_sizes, int n_in,
                              void* d_out, int out_size, void* d_ws, size_t ws_size,
                              hipStream_t stream) {
    const float* means  = (const float*)d_in[0];
    const float* cov    = (const float*)d_in[1];
    const float* color  = (const float*)d_in[2];
    const float* opac   = (const float*)d_in[3];
    const float* depths = (const float*)d_in[4];
    int N = in_sizes[4];

    char* ws = (char*)d_ws;
    size_t off = 0;
    uint32* candCount = (uint32*)(ws + off); off += 256;                    // 4 counters (padded)
    uint32* hist      = (uint32*)(ws + off); off += (size_t)NTILES * NHIST * 4;
    size_t zero_words = off / 4;
    u64*   cand       = (u64*)(ws + off);    off += (size_t)NTILES * N * 8;
    float* params     = (float*)(ws + off);  off += (size_t)NTILES * PMAX * 12 * 4;
    float* partials   = (float*)(ws + off);  off += 6 * PLANE * 4;
    // total ~10.9 MB

    zero_ws<<<(int)((zero_words + 255) / 256), 256, 0, stream>>>((uint32*)d_ws, (int)zero_words);
    preproc<<<(N + 255) / 256, 256, 0, stream>>>(means, cov, depths, candCount, hist, cand, N);
    select_sort<<<NTILES, 1024, 0, stream>>>(hist, candCount, cand, N,
                                             means, cov, color, opac, params);
    render<<<dim3(NPIX / 256, NCHUNK, NTILES), 256, 0, stream>>>(params, partials);
    combine<<<(NTILES * NPIX) / 256, 256, 0, stream>>>(partials, (float*)d_out);
}

// Round 2
// 268.243 us; speedup vs baseline: 1.0153x; 1.0153x over previous
//
#include <hip/hip_runtime.h>

// Problem constants (image 128x128, TILE_SIZE=64)
#define IMG 128
#define TSZ 64
#define NTILES 4          // (128/64)^2
#define PMAX 2048
#define SELCAP 4096       // candidate cap per tile (expected ~2500)
#define NHIST 4096        // depth-bits[31:20] histogram buckets
#define HSHIFT 20
#define NCHUNK 16
#define CHUNK 128         // PMAX / NCHUNK
#define NPIX 4096         // TSZ*TSZ
#define PLANE ((size_t)NTILES * NCHUNK * NPIX)   // 262144 floats per component plane

typedef unsigned int uint32;
typedef unsigned long long u64;

// ---------------------------------------------------------------- zero ws ---
__global__ void zero_ws(uint32* __restrict__ p, int n) {
    int i = blockIdx.x * blockDim.x + threadIdx.x;
    if (i < n) p[i] = 0u;
}

// -------------------------------------------------- shared per-gaussian math
__device__ __forceinline__ void gauss_rect(const float* means, const float* cov,
                                           int i, float& rminx, float& rminy,
                                           float& rmaxx, float& rmaxy) {
    const float4 cv = ((const float4*)cov)[i];           // a, b, c2, d
    float det = cv.x * cv.w - cv.y * cv.z;
    float mid = 0.5f * (cv.x + cv.w);
    float s = sqrtf(fmaxf(mid * mid - det, 0.1f));
    float radius = 3.0f * ceilf(sqrtf(fmaxf(mid + s, mid - s)));
    const float2 m = ((const float2*)means)[i];
    rminx = fminf(fmaxf(m.x - radius, 0.f), (float)(IMG - 1));
    rmaxx = fminf(fmaxf(m.x + radius, 0.f), (float)(IMG - 1));
    rminy = fminf(fmaxf(m.y - radius, 0.f), (float)(IMG - 1));
    rmaxy = fminf(fmaxf(m.y + radius, 0.f), (float)(IMG - 1));
}

__device__ __forceinline__ bool tile_overlap(int t, float rminx, float rminy,
                                             float rmaxx, float rmaxy) {
    float wmin = (float)((t & 1) * TSZ), hmin = (float)((t >> 1) * TSZ);
    float wmax = wmin + (float)(TSZ - 1), hmax = hmin + (float)(TSZ - 1);
    return (fminf(rmaxx, wmax) > fmaxf(rminx, wmin)) &&
           (fminf(rmaxy, hmax) > fmaxf(rminy, hmin));
}

// -------------------------------------------------------------- preprocess --
// Coarse depth histogram (4096 buckets) per tile over overlapping gaussians.
__global__ void preproc(const float* __restrict__ means,
                        const float* __restrict__ cov,
                        const float* __restrict__ depths,
                        uint32* __restrict__ hist,
                        int N) {
    int i = blockIdx.x * blockDim.x + threadIdx.x;
    if (i >= N) return;
    float rminx, rminy, rmaxx, rmaxy;
    gauss_rect(means, cov, i, rminx, rminy, rmaxx, rmaxy);
    uint32 fb = __float_as_uint(depths[i]);              // positive -> monotone bits
    uint32 b = fb >> HSHIFT;
    #pragma unroll
    for (int t = 0; t < NTILES; t++)
        if (tile_overlap(t, rminx, rminy, rmaxx, rmaxy))
            atomicAdd(&hist[t * NHIST + b], 1u);
}

// ------------------------------------------------------------------- findb --
// Per tile: find bucket b* holding the 2048th smallest depth.
__global__ __launch_bounds__(256) void findb(const uint32* __restrict__ hist,
                                             uint32* __restrict__ bstar) {
    int tile = blockIdx.x, tid = threadIdx.x;
    __shared__ uint32 hh[NHIST];
    __shared__ uint32 part[256];
    __shared__ uint32 sB;
    if (tid == 0) sB = NHIST - 1;
    const uint32* h = hist + (size_t)tile * NHIST;
    for (int j = tid; j < NHIST; j += 256) hh[j] = h[j];   // coalesced
    __syncthreads();
    uint32 local = 0;
    #pragma unroll
    for (int b = 0; b < 16; b++) local += hh[tid * 16 + b];
    part[tid] = local;
    __syncthreads();
    for (int off = 1; off < 256; off <<= 1) {
        uint32 v = part[tid];
        uint32 u = (tid >= off) ? part[tid - off] : 0u;
        __syncthreads();
        part[tid] = v + u;
        __syncthreads();
    }
    uint32 incl = part[tid], excl = incl - local;
    if (excl < PMAX && incl >= PMAX) {                    // unique crossing thread
        uint32 cum = excl;
        for (int b = 0; b < 16; b++) {
            cum += hh[tid * 16 + b];
            if (cum >= PMAX) { sB = (uint32)(tid * 16 + b); break; }
        }
    }
    __syncthreads();
    if (tid == 0) bstar[tile] = sB;
}

// ----------------------------------------------------------------- compact --
// Recompute overlap; append keys with bucket <= b* to per-tile candidate list.
__global__ void compact(const float* __restrict__ means,
                        const float* __restrict__ cov,
                        const float* __restrict__ depths,
                        const uint32* __restrict__ bstar,
                        uint32* __restrict__ selCount,
                        u64* __restrict__ sel,
                        int N) {
    int i = blockIdx.x * blockDim.x + threadIdx.x;
    int t = blockIdx.y;
    bool pass = false;
    u64 key = 0;
    if (i < N) {
        float rminx, rminy, rmaxx, rmaxy;
        gauss_rect(means, cov, i, rminx, rminy, rmaxx, rmaxy);
        uint32 fb = __float_as_uint(depths[i]);
        pass = tile_overlap(t, rminx, rminy, rmaxx, rmaxy) && ((fb >> HSHIFT) <= bstar[t]);
        key = ((u64)fb << 32) | (uint32)i;               // stable (depth, idx) order
    }
    int lane = threadIdx.x & 63;
    u64 mask = __ballot(pass);
    if (pass) {
        int leader = __ffsll((unsigned long long)mask) - 1;
        uint32 rank = (uint32)__popcll(mask & ((1ULL << lane) - 1ULL));
        uint32 base = 0;
        if (lane == leader) base = atomicAdd(&selCount[t], (uint32)__popcll(mask));
        base = __shfl(base, leader);
        uint32 pos = base + rank;
        if (pos < SELCAP) sel[(size_t)t * SELCAP + pos] = key;
    }
}

// ------------------------------------------------------------ rank+scatter --
// Exact rank of each candidate = #{j : key_j < key_i} (keys unique). Items
// with rank < PMAX write their render-param record at slot=rank. Spread
// across the whole chip; inner loop is LDS broadcast reads.
__global__ __launch_bounds__(256) void rank_scatter(
        const u64* __restrict__ sel, const uint32* __restrict__ selCount,
        const float* __restrict__ means, const float* __restrict__ cov,
        const float* __restrict__ color, const float* __restrict__ opac,
        float* __restrict__ params) {
    int tile = blockIdx.y;
    uint32 M = selCount[tile]; if (M > SELCAP) M = SELCAP;
    uint32 Mp = (M + 7u) & ~7u;
    __shared__ u64 keys[SELCAP];
    const u64* s = sel + (size_t)tile * SELCAP;
    for (uint32 j = threadIdx.x; j < Mp; j += 256)
        keys[j] = (j < M) ? s[j] : ~0ULL;
    __syncthreads();
    uint32 i = blockIdx.x * 256 + threadIdx.x;
    if (i >= M) return;
    u64 ki = keys[i];
    uint32 r = 0;
    const ulonglong2* k2 = (const ulonglong2*)keys;
    uint32 n2 = Mp >> 1;
    #pragma unroll 8
    for (uint32 j = 0; j < n2; j++) {
        ulonglong2 kk = k2[j];                            // LDS broadcast (16B)
        r += (kk.x < ki) ? 1u : 0u;
        r += (kk.y < ki) ? 1u : 0u;
    }
    if (r < PMAX) {
        uint32 idx = (uint32)(ki & 0xffffffffu);
        float a = cov[4*idx], b = cov[4*idx+1], c2 = cov[4*idx+2], d = cov[4*idx+3];
        float invdet = 1.0f / fmaxf(a * d - b * c2, 1e-6f);
        float4 p0, p1, p2;
        p0.x = means[2*idx]; p0.y = means[2*idx+1];
        p0.z = d * invdet;                 // c00
        p0.w = -(b + c2) * invdet;         // c01 + c10
        p1.x = a * invdet;                 // c11
        p1.y = opac[idx];
        p1.z = color[3*idx]; p1.w = color[3*idx+1];
        p2.x = color[3*idx+2];
        p2.y = __uint_as_float((uint32)(ki >> 32));   // depth
        p2.z = 0.f; p2.w = 0.f;
        float4* P = (float4*)(params + ((size_t)tile * PMAX + r) * 12);
        P[0] = p0; P[1] = p1; P[2] = p2;
    }
}

// ------------------------------------------------------------------ render --
// Block = 256 pixels of one tile, one chunk of 128 gaussians. Front-to-back
// compositing with local T starting at 1; partial (T, sums) per chunk stored
// SoA; combine folds chunks via (T1*T2, S1 + T1*S2).
__global__ __launch_bounds__(256) void render(const float* __restrict__ params,
                                              float* __restrict__ partials) {
    int tile = blockIdx.z, chunk = blockIdx.y;
    int p = blockIdx.x * 256 + threadIdx.x;        // 0..4095 within tile
    __shared__ float4 gp[CHUNK * 3];
    const float4* src = (const float4*)(params + ((size_t)tile * PMAX + (size_t)chunk * CHUNK) * 12);
    for (int j = threadIdx.x; j < CHUNK * 3; j += 256) gp[j] = src[j];
    __syncthreads();

    float px = (float)((tile & 1) * TSZ + (p & 63));
    float py = (float)((tile >> 1) * TSZ + (p >> 6));
    float T = 1.f, cr = 0.f, cg = 0.f, cb = 0.f, dep = 0.f, acc = 0.f;
    #pragma unroll 8
    for (int g = 0; g < CHUNK; g++) {
        float4 p0 = gp[3*g], p1 = gp[3*g+1], p2 = gp[3*g+2];
        float dx = px - p0.x, dy = py - p0.y;
        float power = -0.5f * (dx*dx*p0.z + dy*dy*p1.x + dx*dy*p0.w);
        float alpha = fminf(__expf(power) * p1.y, 0.99f);
        float w = alpha * T;
        cr += w * p1.z; cg += w * p1.w; cb += w * p2.x;
        dep += w * p2.y; acc += w;
        T *= (1.f - alpha);
    }
    size_t base = ((size_t)tile * NCHUNK + chunk) * NPIX + (size_t)p;
    partials[0*PLANE + base] = T;
    partials[1*PLANE + base] = cr;
    partials[2*PLANE + base] = cg;
    partials[3*PLANE + base] = cb;
    partials[4*PLANE + base] = dep;
    partials[5*PLANE + base] = acc;
}

// ----------------------------------------------------------------- combine --
__global__ __launch_bounds__(256) void combine(const float* __restrict__ partials,
                                               float* __restrict__ out) {
    int q = blockIdx.x * 256 + threadIdx.x;        // 0..16383
    int tile = q >> 12, p = q & (NPIX - 1);
    float T = 1.f, cr = 0.f, cg = 0.f, cb = 0.f, dep = 0.f, acc = 0.f;
    #pragma unroll
    for (int c = 0; c < NCHUNK; c++) {
        size_t base = ((size_t)tile * NCHUNK + c) * NPIX + (size_t)p;
        float Tk = partials[0*PLANE + base];
        cr  += T * partials[1*PLANE + base];
        cg  += T * partials[2*PLANE + base];
        cb  += T * partials[3*PLANE + base];
        dep += T * partials[4*PLANE + base];
        acc += T * partials[5*PLANE + base];
        T *= Tk;
    }
    int gx = (tile & 1) * TSZ + (p & 63);
    int gy = (tile >> 1) * TSZ + (p >> 6);
    int pix = gy * IMG + gx;
    float wb = 1.f - acc;                           // WHITE_BKGD
    out[3*pix+0] = cr + wb;
    out[3*pix+1] = cg + wb;
    out[3*pix+2] = cb + wb;
    out[IMG*IMG*3 + pix] = dep;
    out[IMG*IMG*4 + pix] = acc;
}

// ------------------------------------------------------------------ launch --
extern "C" void kernel_launch(void* const* d_in, const int* in_sizes, int n_in,
                              void* d_out, int out_size, void* d_ws, size_t ws_size,
                              hipStream_t stream) {
    const float* means  = (const float*)d_in[0];
    const float* cov    = (const float*)d_in[1];
    const float* color  = (const float*)d_in[2];
    const float* opac   = (const float*)d_in[3];
    const float* depths = (const float*)d_in[4];
    int N = in_sizes[4];

    char* ws = (char*)d_ws;
    size_t off = 0;
    uint32* bstar    = (uint32*)(ws + off); off += 256;
    uint32* selCount = (uint32*)(ws + off); off += 256;
    uint32* hist     = (uint32*)(ws + off); off += (size_t)NTILES * NHIST * 4;   // 64 KB
    float*  params   = (float*)(ws + off);  off += (size_t)NTILES * PMAX * 12 * 4; // 384 KB
    size_t zero_words = off / 4;            // everything above needs zeroing
    u64*    sel      = (u64*)(ws + off);    off += (size_t)NTILES * SELCAP * 8;  // 128 KB
    float*  partials = (float*)(ws + off);  off += 6 * PLANE * 4;                // 6 MB

    zero_ws<<<(int)((zero_words + 255) / 256), 256, 0, stream>>>((uint32*)d_ws, (int)zero_words);
    preproc<<<(N + 255) / 256, 256, 0, stream>>>(means, cov, depths, hist, N);
    findb<<<NTILES, 256, 0, stream>>>(hist, bstar);
    compact<<<dim3((N + 255) / 256, NTILES), 256, 0, stream>>>(means, cov, depths,
                                                               bstar, selCount, sel, N);
    rank_scatter<<<dim3(SELCAP / 256, NTILES), 256, 0, stream>>>(sel, selCount,
                                                                 means, cov, color, opac, params);
    render<<<dim3(NPIX / 256, NCHUNK, NTILES), 256, 0, stream>>>(params, partials);
    combine<<<(NTILES * NPIX) / 256, 256, 0, stream>>>(partials, (float*)d_out);
}

// Round 3
// 193.465 us; speedup vs baseline: 1.4078x; 1.3865x over previous
//
#include <hip/hip_runtime.h>

// Problem constants (image 128x128, TILE_SIZE=64)
#define IMG 128
#define TSZ 64
#define NTILES 4          // (128/64)^2
#define PMAX 2048
#define SELCAP 4096       // candidate cap per tile (expected ~2070)
#define NHIST 4096        // linear depth buckets (width 1/256 depth unit)
#define NCHUNK 16
#define CHUNK 128         // PMAX / NCHUNK
#define NPIX 4096         // TSZ*TSZ
#define PLANE ((size_t)NTILES * NCHUNK * NPIX)   // 262144 floats per component plane

typedef unsigned int uint32;
typedef unsigned long long u64;

// Linear depth bucketing: monotone in depth, uniform occupancy for uniform
// depths (vs float-bits>>20 which concentrates ~56 buckets -> atomic serialization).
__device__ __forceinline__ uint32 dbucket(float d) {
    int b = (int)(d * 256.0f);
    return (uint32)min(max(b, 0), NHIST - 1);
}

// ---------------------------------------------------------------- zero ws ---
__global__ void zero_ws(uint32* __restrict__ p, int n) {
    int i = blockIdx.x * blockDim.x + threadIdx.x;
    if (i < n) p[i] = 0u;
}

// -------------------------------------------------- shared per-gaussian math
__device__ __forceinline__ void gauss_rect(const float* means, const float* cov,
                                           int i, float& rminx, float& rminy,
                                           float& rmaxx, float& rmaxy) {
    const float4 cv = ((const float4*)cov)[i];           // a, b, c2, d
    float det = cv.x * cv.w - cv.y * cv.z;
    float mid = 0.5f * (cv.x + cv.w);
    float s = sqrtf(fmaxf(mid * mid - det, 0.1f));
    float radius = 3.0f * ceilf(sqrtf(fmaxf(mid + s, mid - s)));
    const float2 m = ((const float2*)means)[i];
    rminx = fminf(fmaxf(m.x - radius, 0.f), (float)(IMG - 1));
    rmaxx = fminf(fmaxf(m.x + radius, 0.f), (float)(IMG - 1));
    rminy = fminf(fmaxf(m.y - radius, 0.f), (float)(IMG - 1));
    rmaxy = fminf(fmaxf(m.y + radius, 0.f), (float)(IMG - 1));
}

__device__ __forceinline__ bool tile_overlap(int t, float rminx, float rminy,
                                             float rmaxx, float rmaxy) {
    float wmin = (float)((t & 1) * TSZ), hmin = (float)((t >> 1) * TSZ);
    float wmax = wmin + (float)(TSZ - 1), hmax = hmin + (float)(TSZ - 1);
    return (fminf(rmaxx, wmax) > fmaxf(rminx, wmin)) &&
           (fminf(rmaxy, hmax) > fmaxf(rminy, hmin));
}

// -------------------------------------------------------------- preprocess --
// Linear depth histogram per tile over overlapping gaussians. ~190k atomics
// spread over ~2600 populated buckets/tile -> negligible contention.
__global__ void preproc(const float* __restrict__ means,
                        const float* __restrict__ cov,
                        const float* __restrict__ depths,
                        uint32* __restrict__ hist,
                        int N) {
    int i = blockIdx.x * blockDim.x + threadIdx.x;
    if (i >= N) return;
    float rminx, rminy, rmaxx, rmaxy;
    gauss_rect(means, cov, i, rminx, rminy, rmaxx, rmaxy);
    uint32 b = dbucket(depths[i]);
    #pragma unroll
    for (int t = 0; t < NTILES; t++)
        if (tile_overlap(t, rminx, rminy, rmaxx, rmaxy))
            atomicAdd(&hist[t * NHIST + b], 1u);
}

// ------------------------------------------------------------------- findb --
// Per tile: find bucket b* holding the 2048th smallest depth.
__global__ __launch_bounds__(256) void findb(const uint32* __restrict__ hist,
                                             uint32* __restrict__ bstar) {
    int tile = blockIdx.x, tid = threadIdx.x;
    __shared__ uint32 hh[NHIST];
    __shared__ uint32 part[256];
    __shared__ uint32 sB;
    if (tid == 0) sB = NHIST - 1;
    const uint32* h = hist + (size_t)tile * NHIST;
    for (int j = tid; j < NHIST; j += 256) hh[j] = h[j];   // coalesced
    __syncthreads();
    uint32 local = 0;
    #pragma unroll
    for (int b = 0; b < 16; b++) local += hh[tid * 16 + b];
    part[tid] = local;
    __syncthreads();
    for (int off = 1; off < 256; off <<= 1) {
        uint32 v = part[tid];
        uint32 u = (tid >= off) ? part[tid - off] : 0u;
        __syncthreads();
        part[tid] = v + u;
        __syncthreads();
    }
    uint32 incl = part[tid], excl = incl - local;
    if (excl < PMAX && incl >= PMAX) {                    // unique crossing thread
        uint32 cum = excl;
        for (int b = 0; b < 16; b++) {
            cum += hh[tid * 16 + b];
            if (cum >= PMAX) { sB = (uint32)(tid * 16 + b); break; }
        }
    }
    __syncthreads();
    if (tid == 0) bstar[tile] = sB;
}

// ----------------------------------------------------------------- compact --
// Recompute overlap; append keys with bucket <= b* to per-tile candidate list.
__global__ void compact(const float* __restrict__ means,
                        const float* __restrict__ cov,
                        const float* __restrict__ depths,
                        const uint32* __restrict__ bstar,
                        uint32* __restrict__ selCount,
                        u64* __restrict__ sel,
                        int N) {
    int i = blockIdx.x * blockDim.x + threadIdx.x;
    int t = blockIdx.y;
    bool pass = false;
    u64 key = 0;
    if (i < N) {
        float rminx, rminy, rmaxx, rmaxy;
        gauss_rect(means, cov, i, rminx, rminy, rmaxx, rmaxy);
        float d = depths[i];
        pass = tile_overlap(t, rminx, rminy, rmaxx, rmaxy) && (dbucket(d) <= bstar[t]);
        key = ((u64)__float_as_uint(d) << 32) | (uint32)i;  // stable (depth, idx) order
    }
    int lane = threadIdx.x & 63;
    u64 mask = __ballot(pass);
    if (pass) {
        int leader = __ffsll((unsigned long long)mask) - 1;
        uint32 rank = (uint32)__popcll(mask & ((1ULL << lane) - 1ULL));
        uint32 base = 0;
        if (lane == leader) base = atomicAdd(&selCount[t], (uint32)__popcll(mask));
        base = __shfl(base, leader);
        uint32 pos = base + rank;
        if (pos < SELCAP) sel[(size_t)t * SELCAP + pos] = key;
    }
}

// ------------------------------------------------------------ rank+scatter --
// Exact rank of each candidate = #{j : key_j < key_i} (keys unique). Items
// with rank < PMAX write their render-param record at slot=rank.
__global__ __launch_bounds__(256) void rank_scatter(
        const u64* __restrict__ sel, const uint32* __restrict__ selCount,
        const float* __restrict__ means, const float* __restrict__ cov,
        const float* __restrict__ color, const float* __restrict__ opac,
        float* __restrict__ params) {
    int tile = blockIdx.y;
    uint32 M = selCount[tile]; if (M > SELCAP) M = SELCAP;
    uint32 Mp = (M + 7u) & ~7u;
    __shared__ u64 keys[SELCAP];
    const u64* s = sel + (size_t)tile * SELCAP;
    for (uint32 j = threadIdx.x; j < Mp; j += 256)
        keys[j] = (j < M) ? s[j] : ~0ULL;
    __syncthreads();
    uint32 i = blockIdx.x * 256 + threadIdx.x;
    if (i >= M) return;
    u64 ki = keys[i];
    uint32 r = 0;
    const ulonglong2* k2 = (const ulonglong2*)keys;
    uint32 n2 = Mp >> 1;
    #pragma unroll 8
    for (uint32 j = 0; j < n2; j++) {
        ulonglong2 kk = k2[j];                            // LDS broadcast (16B)
        r += (kk.x < ki) ? 1u : 0u;
        r += (kk.y < ki) ? 1u : 0u;
    }
    if (r < PMAX) {
        uint32 idx = (uint32)(ki & 0xffffffffu);
        float a = cov[4*idx], b = cov[4*idx+1], c2 = cov[4*idx+2], d = cov[4*idx+3];
        float invdet = 1.0f / fmaxf(a * d - b * c2, 1e-6f);
        float4 p0, p1, p2;
        p0.x = means[2*idx]; p0.y = means[2*idx+1];
        p0.z = d * invdet;                 // c00
        p0.w = -(b + c2) * invdet;         // c01 + c10
        p1.x = a * invdet;                 // c11
        p1.y = opac[idx];
        p1.z = color[3*idx]; p1.w = color[3*idx+1];
        p2.x = color[3*idx+2];
        p2.y = __uint_as_float((uint32)(ki >> 32));   // depth
        p2.z = 0.f; p2.w = 0.f;
        float4* P = (float4*)(params + ((size_t)tile * PMAX + r) * 12);
        P[0] = p0; P[1] = p1; P[2] = p2;
    }
}

// ------------------------------------------------------------------ render --
// Block = 256 pixels of one tile, one chunk of 128 gaussians. Front-to-back
// compositing with local T starting at 1; partial (T, sums) per chunk stored
// SoA; combine folds chunks via (T1*T2, S1 + T1*S2).
__global__ __launch_bounds__(256) void render(const float* __restrict__ params,
                                              float* __restrict__ partials) {
    int tile = blockIdx.z, chunk = blockIdx.y;
    int p = blockIdx.x * 256 + threadIdx.x;        // 0..4095 within tile
    __shared__ float4 gp[CHUNK * 3];
    const float4* src = (const float4*)(params + ((size_t)tile * PMAX + (size_t)chunk * CHUNK) * 12);
    for (int j = threadIdx.x; j < CHUNK * 3; j += 256) gp[j] = src[j];
    __syncthreads();

    float px = (float)((tile & 1) * TSZ + (p & 63));
    float py = (float)((tile >> 1) * TSZ + (p >> 6));
    float T = 1.f, cr = 0.f, cg = 0.f, cb = 0.f, dep = 0.f, acc = 0.f;
    #pragma unroll 8
    for (int g = 0; g < CHUNK; g++) {
        float4 p0 = gp[3*g], p1 = gp[3*g+1], p2 = gp[3*g+2];
        float dx = px - p0.x, dy = py - p0.y;
        float power = -0.5f * (dx*dx*p0.z + dy*dy*p1.x + dx*dy*p0.w);
        float alpha = fminf(__expf(power) * p1.y, 0.99f);
        float w = alpha * T;
        cr += w * p1.z; cg += w * p1.w; cb += w * p2.x;
        dep += w * p2.y; acc += w;
        T *= (1.f - alpha);
    }
    size_t base = ((size_t)tile * NCHUNK + chunk) * NPIX + (size_t)p;
    partials[0*PLANE + base] = T;
    partials[1*PLANE + base] = cr;
    partials[2*PLANE + base] = cg;
    partials[3*PLANE + base] = cb;
    partials[4*PLANE + base] = dep;
    partials[5*PLANE + base] = acc;
}

// ----------------------------------------------------------------- combine --
__global__ __launch_bounds__(256) void combine(const float* __restrict__ partials,
                                               float* __restrict__ out) {
    int q = blockIdx.x * 256 + threadIdx.x;        // 0..16383
    int tile = q >> 12, p = q & (NPIX - 1);
    float T = 1.f, cr = 0.f, cg = 0.f, cb = 0.f, dep = 0.f, acc = 0.f;
    #pragma unroll
    for (int c = 0; c < NCHUNK; c++) {
        size_t base = ((size_t)tile * NCHUNK + c) * NPIX + (size_t)p;
        float Tk = partials[0*PLANE + base];
        cr  += T * partials[1*PLANE + base];
        cg  += T * partials[2*PLANE + base];
        cb  += T * partials[3*PLANE + base];
        dep += T * partials[4*PLANE + base];
        acc += T * partials[5*PLANE + base];
        T *= Tk;
    }
    int gx = (tile & 1) * TSZ + (p & 63);
    int gy = (tile >> 1) * TSZ + (p >> 6);
    int pix = gy * IMG + gx;
    float wb = 1.f - acc;                           // WHITE_BKGD
    out[3*pix+0] = cr + wb;
    out[3*pix+1] = cg + wb;
    out[3*pix+2] = cb + wb;
    out[IMG*IMG*3 + pix] = dep;
    out[IMG*IMG*4 + pix] = acc;
}

// ------------------------------------------------------------------ launch --
extern "C" void kernel_launch(void* const* d_in, const int* in_sizes, int n_in,
                              void* d_out, int out_size, void* d_ws, size_t ws_size,
                              hipStream_t stream) {
    const float* means  = (const float*)d_in[0];
    const float* cov    = (const float*)d_in[1];
    const float* color  = (const float*)d_in[2];
    const float* opac   = (const float*)d_in[3];
    const float* depths = (const float*)d_in[4];
    int N = in_sizes[4];

    char* ws = (char*)d_ws;
    size_t off = 0;
    uint32* bstar    = (uint32*)(ws + off); off += 256;
    uint32* selCount = (uint32*)(ws + off); off += 256;
    uint32* hist     = (uint32*)(ws + off); off += (size_t)NTILES * NHIST * 4;   // 64 KB
    float*  params   = (float*)(ws + off);  off += (size_t)NTILES * PMAX * 12 * 4; // 384 KB
    size_t zero_words = off / 4;            // everything above needs zeroing
    u64*    sel      = (u64*)(ws + off);    off += (size_t)NTILES * SELCAP * 8;  // 128 KB
    float*  partials = (float*)(ws + off);  off += 6 * PLANE * 4;                // 6 MB

    zero_ws<<<(int)((zero_words + 255) / 256), 256, 0, stream>>>((uint32*)d_ws, (int)zero_words);
    preproc<<<(N + 255) / 256, 256, 0, stream>>>(means, cov, depths, hist, N);
    findb<<<NTILES, 256, 0, stream>>>(hist, bstar);
    compact<<<dim3((N + 255) / 256, NTILES), 256, 0, stream>>>(means, cov, depths,
                                                               bstar, selCount, sel, N);
    rank_scatter<<<dim3(SELCAP / 256, NTILES), 256, 0, stream>>>(sel, selCount,
                                                                 means, cov, color, opac, params);
    render<<<dim3(NPIX / 256, NCHUNK, NTILES), 256, 0, stream>>>(params, partials);
    combine<<<(NTILES * NPIX) / 256, 256, 0, stream>>>(partials, (float*)d_out);
}

// Round 4
// 146.043 us; speedup vs baseline: 1.8649x; 1.3247x over previous
//
#include <hip/hip_runtime.h>

// Problem constants (image 128x128, TILE_SIZE=64)
#define IMG 128
#define TSZ 64
#define NTILES 4          // (128/64)^2
#define PMAX 2048
#define SELCAP 4096       // candidate cap per tile (expected ~2070)
#define NHIST 4096        // linear depth buckets (width 1/256 depth unit)
#define NCHUNK 16
#define CHUNK 128         // PMAX / NCHUNK
#define NPIX 4096         // TSZ*TSZ
#define PLANE ((size_t)NTILES * NCHUNK * NPIX)   // 262144 floats per component plane

typedef unsigned short u16;
typedef unsigned int uint32;
typedef unsigned long long u64;

// Linear depth bucketing: monotone in depth, uniform occupancy for uniform
// depths (float-bits>>20 concentrated ~56 buckets -> atomic serialization).
__device__ __forceinline__ uint32 dbucket(float d) {
    int b = (int)(d * 256.0f);
    return (uint32)min(max(b, 0), NHIST - 1);
}

// ---------------------------------------------------------------- zero ws ---
__global__ void zero_ws(uint32* __restrict__ p, int n) {
    int i = blockIdx.x * blockDim.x + threadIdx.x;
    if (i < n) p[i] = 0u;
}

// -------------------------------------------------- shared per-gaussian math
__device__ __forceinline__ void gauss_rect(const float* means, const float* cov,
                                           int i, float& rminx, float& rminy,
                                           float& rmaxx, float& rmaxy) {
    const float4 cv = ((const float4*)cov)[i];           // a, b, c2, d
    float det = cv.x * cv.w - cv.y * cv.z;
    float mid = 0.5f * (cv.x + cv.w);
    float s = sqrtf(fmaxf(mid * mid - det, 0.1f));
    float radius = 3.0f * ceilf(sqrtf(fmaxf(mid + s, mid - s)));
    const float2 m = ((const float2*)means)[i];
    rminx = fminf(fmaxf(m.x - radius, 0.f), (float)(IMG - 1));
    rmaxx = fminf(fmaxf(m.x + radius, 0.f), (float)(IMG - 1));
    rminy = fminf(fmaxf(m.y - radius, 0.f), (float)(IMG - 1));
    rmaxy = fminf(fmaxf(m.y + radius, 0.f), (float)(IMG - 1));
}

__device__ __forceinline__ bool tile_overlap(int t, float rminx, float rminy,
                                             float rmaxx, float rmaxy) {
    float wmin = (float)((t & 1) * TSZ), hmin = (float)((t >> 1) * TSZ);
    float wmax = wmin + (float)(TSZ - 1), hmax = hmin + (float)(TSZ - 1);
    return (fminf(rmaxx, wmax) > fmaxf(rminx, wmin)) &&
           (fminf(rmaxy, hmax) > fmaxf(rminy, hmin));
}

// -------------------------------------------------------------- preprocess --
// Per-tile linear depth histogram + packed (tileMask<<12)|bucket per gaussian.
__global__ void preproc(const float* __restrict__ means,
                        const float* __restrict__ cov,
                        const float* __restrict__ depths,
                        uint32* __restrict__ hist,
                        u16* __restrict__ tmb,
                        int N) {
    int i = blockIdx.x * blockDim.x + threadIdx.x;
    if (i >= N) return;
    float rminx, rminy, rmaxx, rmaxy;
    gauss_rect(means, cov, i, rminx, rminy, rmaxx, rmaxy);
    uint32 b = dbucket(depths[i]);
    uint32 mask = 0;
    #pragma unroll
    for (int t = 0; t < NTILES; t++) {
        if (tile_overlap(t, rminx, rminy, rmaxx, rmaxy)) {
            mask |= (1u << t);
            atomicAdd(&hist[t * NHIST + b], 1u);
        }
    }
    tmb[i] = (u16)((mask << 12) | b);
}

// ------------------------------------------------------------------- findb --
// Per tile: threshold bucket b* holding the 2048th smallest depth, exclusive
// bucket prefix-sum bucketBase[], and exact candidate count selCount.
__global__ __launch_bounds__(256) void findb(const uint32* __restrict__ hist,
                                             uint32* __restrict__ bstar,
                                             uint32* __restrict__ selCount,
                                             uint32* __restrict__ bucketBase) {
    int tile = blockIdx.x, tid = threadIdx.x;
    __shared__ uint32 hh[NHIST];
    __shared__ uint32 part[256];
    __shared__ uint32 sB, sM;
    if (tid == 0) { sB = NHIST - 1; sM = 0; }
    const uint32* h = hist + (size_t)tile * NHIST;
    for (int j = tid; j < NHIST; j += 256) hh[j] = h[j];   // coalesced
    __syncthreads();
    uint32 local = 0;
    #pragma unroll
    for (int b = 0; b < 16; b++) local += hh[tid * 16 + b];
    part[tid] = local;
    __syncthreads();
    for (int off = 1; off < 256; off <<= 1) {
        uint32 v = part[tid];
        uint32 u = (tid >= off) ? part[tid - off] : 0u;
        __syncthreads();
        part[tid] = v + u;
        __syncthreads();
    }
    uint32 incl = part[tid], excl = incl - local;
    // write exclusive bucket bases (deterministic compact positions)
    uint32 run = excl;
    #pragma unroll
    for (int b = 0; b < 16; b++) {
        uint32 j = (uint32)(tid * 16 + b);
        bucketBase[(size_t)tile * NHIST + j] = run;
        run += hh[j];
    }
    if (excl < PMAX && incl >= PMAX) {                    // unique crossing thread
        uint32 cum = excl;
        for (int b = 0; b < 16; b++) {
            cum += hh[tid * 16 + b];
            if (cum >= PMAX) { sB = (uint32)(tid * 16 + b); sM = cum; break; }
        }
    }
    __syncthreads();
    if (tid == 0) {
        bstar[tile] = sB;
        selCount[tile] = (sM != 0) ? sM : part[255];      // count through b*
    }
}

// ----------------------------------------------------------------- compact --
// Deterministic scatter: pos = bucketBase[b] + fill within bucket. Atomics
// spread over ~2000 populated buckets/tile (~4 per address, uncontended) vs
// previous single selCount[t] (1563 serialized round-trips = 56 us).
__global__ void compact(const u16* __restrict__ tmb,
                        const float* __restrict__ depths,
                        const uint32* __restrict__ bstar,
                        const uint32* __restrict__ bucketBase,
                        uint32* __restrict__ bucketFill,
                        u64* __restrict__ sel,
                        int N) {
    int i = blockIdx.x * blockDim.x + threadIdx.x;
    if (i >= N) return;
    uint32 tm = tmb[i];
    uint32 mask = tm >> 12;
    if (!mask) return;
    uint32 b = tm & 0xFFFu;
    u64 key = ((u64)__float_as_uint(depths[i]) << 32) | (uint32)i;
    #pragma unroll
    for (int t = 0; t < NTILES; t++) {
        if (((mask >> t) & 1u) && b <= bstar[t]) {
            uint32 pos = bucketBase[(size_t)t * NHIST + b]
                       + atomicAdd(&bucketFill[(size_t)t * NHIST + b], 1u);
            if (pos < SELCAP) sel[(size_t)t * SELCAP + pos] = key;
        }
    }
}

// ------------------------------------------------------------ rank+scatter --
// Exact rank of each candidate = #{j : key_j < key_i} (keys unique). Items
// with rank < PMAX write their render-param record at slot=rank.
__global__ __launch_bounds__(256) void rank_scatter(
        const u64* __restrict__ sel, const uint32* __restrict__ selCount,
        const float* __restrict__ means, const float* __restrict__ cov,
        const float* __restrict__ color, const float* __restrict__ opac,
        float* __restrict__ params) {
    int tile = blockIdx.y;
    uint32 M = selCount[tile]; if (M > SELCAP) M = SELCAP;
    uint32 Mp = (M + 7u) & ~7u;
    __shared__ u64 keys[SELCAP];
    const u64* s = sel + (size_t)tile * SELCAP;
    for (uint32 j = threadIdx.x; j < Mp; j += 256)
        keys[j] = (j < M) ? s[j] : ~0ULL;
    __syncthreads();
    uint32 i = blockIdx.x * 256 + threadIdx.x;
    if (i >= M) return;
    u64 ki = keys[i];
    uint32 r = 0;
    const ulonglong2* k2 = (const ulonglong2*)keys;
    uint32 n2 = Mp >> 1;
    #pragma unroll 8
    for (uint32 j = 0; j < n2; j++) {
        ulonglong2 kk = k2[j];                            // LDS broadcast (16B)
        r += (kk.x < ki) ? 1u : 0u;
        r += (kk.y < ki) ? 1u : 0u;
    }
    if (r < PMAX) {
        uint32 idx = (uint32)(ki & 0xffffffffu);
        float a = cov[4*idx], b = cov[4*idx+1], c2 = cov[4*idx+2], d = cov[4*idx+3];
        float invdet = 1.0f / fmaxf(a * d - b * c2, 1e-6f);
        float4 p0, p1, p2;
        p0.x = means[2*idx]; p0.y = means[2*idx+1];
        p0.z = d * invdet;                 // c00
        p0.w = -(b + c2) * invdet;         // c01 + c10
        p1.x = a * invdet;                 // c11
        p1.y = opac[idx];
        p1.z = color[3*idx]; p1.w = color[3*idx+1];
        p2.x = color[3*idx+2];
        p2.y = __uint_as_float((uint32)(ki >> 32));   // depth
        p2.z = 0.f; p2.w = 0.f;
        float4* P = (float4*)(params + ((size_t)tile * PMAX + r) * 12);
        P[0] = p0; P[1] = p1; P[2] = p2;
    }
}

// ------------------------------------------------------------------ render --
// Block = 256 pixels of one tile, one chunk of 128 gaussians. Front-to-back
// compositing with local T starting at 1; partial (T, sums) per chunk stored
// SoA; combine folds chunks via (T1*T2, S1 + T1*S2).
__global__ __launch_bounds__(256) void render(const float* __restrict__ params,
                                              float* __restrict__ partials) {
    int tile = blockIdx.z, chunk = blockIdx.y;
    int p = blockIdx.x * 256 + threadIdx.x;        // 0..4095 within tile
    __shared__ float4 gp[CHUNK * 3];
    const float4* src = (const float4*)(params + ((size_t)tile * PMAX + (size_t)chunk * CHUNK) * 12);
    for (int j = threadIdx.x; j < CHUNK * 3; j += 256) gp[j] = src[j];
    __syncthreads();

    float px = (float)((tile & 1) * TSZ + (p & 63));
    float py = (float)((tile >> 1) * TSZ + (p >> 6));
    float T = 1.f, cr = 0.f, cg = 0.f, cb = 0.f, dep = 0.f, acc = 0.f;
    #pragma unroll 8
    for (int g = 0; g < CHUNK; g++) {
        float4 p0 = gp[3*g], p1 = gp[3*g+1], p2 = gp[3*g+2];
        float dx = px - p0.x, dy = py - p0.y;
        float power = -0.5f * (dx*dx*p0.z + dy*dy*p1.x + dx*dy*p0.w);
        float alpha = fminf(__expf(power) * p1.y, 0.99f);
        float w = alpha * T;
        cr += w * p1.z; cg += w * p1.w; cb += w * p2.x;
        dep += w * p2.y; acc += w;
        T *= (1.f - alpha);
    }
    size_t base = ((size_t)tile * NCHUNK + chunk) * NPIX + (size_t)p;
    partials[0*PLANE + base] = T;
    partials[1*PLANE + base] = cr;
    partials[2*PLANE + base] = cg;
    partials[3*PLANE + base] = cb;
    partials[4*PLANE + base] = dep;
    partials[5*PLANE + base] = acc;
}

// ----------------------------------------------------------------- combine --
__global__ __launch_bounds__(256) void combine(const float* __restrict__ partials,
                                               float* __restrict__ out) {
    int q = blockIdx.x * 256 + threadIdx.x;        // 0..16383
    int tile = q >> 12, p = q & (NPIX - 1);
    float T = 1.f, cr = 0.f, cg = 0.f, cb = 0.f, dep = 0.f, acc = 0.f;
    #pragma unroll
    for (int c = 0; c < NCHUNK; c++) {
        size_t base = ((size_t)tile * NCHUNK + c) * NPIX + (size_t)p;
        float Tk = partials[0*PLANE + base];
        cr  += T * partials[1*PLANE + base];
        cg  += T * partials[2*PLANE + base];
        cb  += T * partials[3*PLANE + base];
        dep += T * partials[4*PLANE + base];
        acc += T * partials[5*PLANE + base];
        T *= Tk;
    }
    int gx = (tile & 1) * TSZ + (p & 63);
    int gy = (tile >> 1) * TSZ + (p >> 6);
    int pix = gy * IMG + gx;
    float wb = 1.f - acc;                           // WHITE_BKGD
    out[3*pix+0] = cr + wb;
    out[3*pix+1] = cg + wb;
    out[3*pix+2] = cb + wb;
    out[IMG*IMG*3 + pix] = dep;
    out[IMG*IMG*4 + pix] = acc;
}

// ------------------------------------------------------------------ launch --
extern "C" void kernel_launch(void* const* d_in, const int* in_sizes, int n_in,
                              void* d_out, int out_size, void* d_ws, size_t ws_size,
                              hipStream_t stream) {
    const float* means  = (const float*)d_in[0];
    const float* cov    = (const float*)d_in[1];
    const float* color  = (const float*)d_in[2];
    const float* opac   = (const float*)d_in[3];
    const float* depths = (const float*)d_in[4];
    int N = in_sizes[4];

    char* ws = (char*)d_ws;
    size_t off = 0;
    // --- zeroed region first ---
    uint32* hist       = (uint32*)(ws + off); off += (size_t)NTILES * NHIST * 4;   // 64 KB
    uint32* bucketFill = (uint32*)(ws + off); off += (size_t)NTILES * NHIST * 4;   // 64 KB
    float*  params     = (float*)(ws + off);  off += (size_t)NTILES * PMAX * 12 * 4; // 384 KB
    size_t zero_words = off / 4;
    // --- written-every-call region (no zeroing needed) ---
    uint32* bstar      = (uint32*)(ws + off); off += 256;
    uint32* selCount   = (uint32*)(ws + off); off += 256;
    uint32* bucketBase = (uint32*)(ws + off); off += (size_t)NTILES * NHIST * 4;   // 64 KB
    u16*    tmb        = (u16*)(ws + off);    off += ((size_t)N * 2 + 255) & ~255ull;
    u64*    sel        = (u64*)(ws + off);    off += (size_t)NTILES * SELCAP * 8;  // 128 KB
    float*  partials   = (float*)(ws + off);  off += 6 * PLANE * 4;                // 6 MB

    zero_ws<<<(int)((zero_words + 255) / 256), 256, 0, stream>>>((uint32*)d_ws, (int)zero_words);
    preproc<<<(N + 255) / 256, 256, 0, stream>>>(means, cov, depths, hist, tmb, N);
    findb<<<NTILES, 256, 0, stream>>>(hist, bstar, selCount, bucketBase);
    compact<<<(N + 255) / 256, 256, 0, stream>>>(tmb, depths, bstar, bucketBase,
                                                 bucketFill, sel, N);
    rank_scatter<<<dim3(SELCAP / 256, NTILES), 256, 0, stream>>>(sel, selCount,
                                                                 means, cov, color, opac, params);
    render<<<dim3(NPIX / 256, NCHUNK, NTILES), 256, 0, stream>>>(params, partials);
    combine<<<(NTILES * NPIX) / 256, 256, 0, stream>>>(partials, (float*)d_out);
}